// Round 2
// baseline (1101.959 us; speedup 1.0000x reference)
//
#include <hip/hip_runtime.h>
#include <hip/hip_bf16.h>
#include <cstdint>

// MoE top-2 of 8, N=32768 tokens, D=1024.
// Strategy: fp32 -> (bf16 hi, bf16 lo) split; out = hi*Whi + hi*Wlo + lo*Whi
// as a grouped GEMM with K_eff = 3*1024. Two passes (slot0 write, slot1 +=)
// so no atomics. m97-style 128x128 tile, 16x16x32 bf16 MFMA, global_load_lds.
// ws requirement ~161 MiB.

#define N_TOK 32768
#define DIM   1024
#define NEXP  8
#define BM    128
#define BK    32
#define NTM   263           // max sum_e ceil(n_e/128), sum n_e = 32768

typedef __attribute__((ext_vector_type(8))) short short8;   // 8 bf16
typedef __attribute__((ext_vector_type(4))) float f32x4;
typedef unsigned short u16;

struct Ctrl {
  int counts[16];      // [slot][expert] -- memset to 0 each launch (64 B)
  int cursors[16];
  int ntiles[2];
  int pad[30];
  int4 table[2 * NTM]; // {expert, start_in_slot_list, rows, 0}
};

__device__ __forceinline__ void gload_lds16(void* lds, const void* g) {
  __builtin_amdgcn_global_load_lds(
      (const __attribute__((address_space(1))) void*)g,
      (__attribute__((address_space(3))) void*)lds, 16, 0, 0);
}

// split: hi = truncate-to-bf16(x); lo = truncate-to-bf16(x - hi); residual ~2^-16 rel
__device__ __forceinline__ void splitf(float f, u16& h, u16& l) {
  uint32_t u = __float_as_uint(f);
  h = (u16)(u >> 16);
  float r = f - __uint_as_float(u & 0xFFFF0000u);   // exact in f32
  l = (u16)(__float_as_uint(r) >> 16);
}

// ---------------- expert weight conversion ----------------
extern "C" __global__ __launch_bounds__(256) void k_convert_w(
    const float4* __restrict__ W, ushort4* __restrict__ Wh, ushort4* __restrict__ Wl) {
  const int total = NEXP * DIM * DIM / 4;
  for (int i = blockIdx.x * 256 + threadIdx.x; i < total; i += gridDim.x * 256) {
    float4 v = W[i];
    u16 hx, lx, hy, ly, hz, lz, hw, lw;
    splitf(v.x, hx, lx); splitf(v.y, hy, ly);
    splitf(v.z, hz, lz); splitf(v.w, hw, lw);
    Wh[i] = make_ushort4(hx, hy, hz, hw);
    Wl[i] = make_ushort4(lx, ly, lz, lw);
  }
}

// ---------------- gating + x conversion (fused) ----------------
// one wave per token; gate_W staged in LDS (32 KB f32)
extern "C" __global__ __launch_bounds__(256) void k_gate(
    const float* __restrict__ x, const float* __restrict__ gW,
    const float* __restrict__ gb, u16* __restrict__ xh, u16* __restrict__ xl,
    float* __restrict__ wts, int* __restrict__ eids, int* __restrict__ counts) {
  __shared__ float4 gwl[NEXP * 256];   // [e][256] float4
  __shared__ int cnt[16];
  int tid = threadIdx.x;
  for (int i = tid; i < NEXP * 256; i += 256) gwl[i] = ((const float4*)gW)[i];
  if (tid < 16) cnt[tid] = 0;
  __syncthreads();

  float gbr[NEXP];
#pragma unroll
  for (int e = 0; e < NEXP; ++e) gbr[e] = gb[e];

  int lane = tid & 63, wid = tid >> 6;
  int wave = blockIdx.x * 4 + wid;            // 2048 waves total
  for (int t = wave; t < N_TOK; t += 2048) {  // 16 iters, uniform
    const float4* xr = (const float4*)(x + (size_t)t * DIM);
    float acc[NEXP] = {0,0,0,0,0,0,0,0};
    float4 xv[4];
#pragma unroll
    for (int j = 0; j < 4; ++j) {
      float4 v = xr[j * 64 + lane];
      xv[j] = v;
#pragma unroll
      for (int e = 0; e < NEXP; ++e) {
        float4 g = gwl[e * 256 + j * 64 + lane];
        acc[e] += v.x * g.x + v.y * g.y + v.z * g.z + v.w * g.w;
      }
    }
#pragma unroll
    for (int off = 32; off > 0; off >>= 1)
#pragma unroll
      for (int e = 0; e < NEXP; ++e) acc[e] += __shfl_xor(acc[e], off, 64);

#pragma unroll
    for (int e = 0; e < NEXP; ++e) acc[e] += gbr[e];

    float m = acc[0];
#pragma unroll
    for (int e = 1; e < NEXP; ++e) m = fmaxf(m, acc[e]);
    float p[NEXP], s = 0.f;
#pragma unroll
    for (int e = 0; e < NEXP; ++e) { p[e] = expf(acc[e] - m); s += p[e]; }
    float inv = 1.f / s;

    // top-1 / top-2 (ties -> lower index, matching lax.top_k)
    int i0 = 0; float b0 = acc[0];
#pragma unroll
    for (int e = 1; e < NEXP; ++e) if (acc[e] > b0) { b0 = acc[e]; i0 = e; }
    int i1 = -1; float b1 = -3.4e38f;
#pragma unroll
    for (int e = 0; e < NEXP; ++e)
      if (e != i0 && acc[e] > b1) { b1 = acc[e]; i1 = e; }

    if (lane == 0) {
      wts[t * 2 + 0] = p[i0] * inv;   // full softmax prob (not renormalized)
      wts[t * 2 + 1] = p[i1] * inv;
      eids[t * 2 + 0] = i0;
      eids[t * 2 + 1] = i1;
      atomicAdd(&cnt[i0], 1);
      atomicAdd(&cnt[8 + i1], 1);
    }
    // x -> hi/lo bf16
    ushort4* oh = (ushort4*)(xh + (size_t)t * DIM);
    ushort4* ol = (ushort4*)(xl + (size_t)t * DIM);
#pragma unroll
    for (int j = 0; j < 4; ++j) {
      u16 hx, lx, hy, ly, hz, lz, hw, lw;
      splitf(xv[j].x, hx, lx); splitf(xv[j].y, hy, ly);
      splitf(xv[j].z, hz, lz); splitf(xv[j].w, hw, lw);
      oh[j * 64 + lane] = make_ushort4(hx, hy, hz, hw);
      ol[j * 64 + lane] = make_ushort4(lx, ly, lz, lw);
    }
  }
  __syncthreads();
  if (tid < 16) atomicAdd(&counts[tid], cnt[tid]);
}

// ---------------- scan + tile schedule ----------------
extern "C" __global__ void k_scan(Ctrl* ctrl) {
  if (threadIdx.x == 0) {
    for (int s = 0; s < 2; ++s) {
      int off = 0, nt = 0;
      for (int e = 0; e < NEXP; ++e) {
        int c = ctrl->counts[s * 8 + e];
        ctrl->cursors[s * 8 + e] = off;
        int tcnt = (c + BM - 1) >> 7;
        for (int i = 0; i < tcnt; ++i)
          ctrl->table[s * NTM + nt + i] =
              make_int4(e, off + i * BM, min(BM, c - i * BM), 0);
        nt += tcnt; off += c;
      }
      ctrl->ntiles[s] = nt;
    }
  }
}

// ---------------- build per-(slot,expert) token lists ----------------
extern "C" __global__ __launch_bounds__(256) void k_lists(
    const int* __restrict__ eids, int* __restrict__ cursors, int* __restrict__ lists) {
  int t = blockIdx.x * 256 + threadIdx.x;
  int lane = threadIdx.x & 63;
#pragma unroll
  for (int s = 0; s < 2; ++s) {
    int e = eids[t * 2 + s];
#pragma unroll
    for (int ex = 0; ex < NEXP; ++ex) {
      unsigned long long msk = __ballot(e == ex);
      if (msk) {
        int leader = __ffsll((unsigned long long)msk) - 1;
        int base = 0;
        if (lane == leader) base = atomicAdd(&cursors[s * 8 + ex], (int)__popcll(msk));
        base = __shfl(base, leader, 64);
        if (e == ex) {
          int pos = base + (int)__popcll(msk & ((1ull << lane) - 1ull));
          lists[s * N_TOK + pos] = t;
        }
      }
    }
  }
}

// ---------------- grouped GEMM (one slot per launch) ----------------
// 128x128 tile; 3 split-terms x K=1024 (term 0: xh*Wh, 1: xh*Wl, 2: xl*Wh).
extern "C" __global__ __launch_bounds__(256) void k_gemm(
    int slot, const u16* __restrict__ xh, const u16* __restrict__ xl,
    const u16* __restrict__ Wh, const u16* __restrict__ Wl,
    const float* __restrict__ eb, const float* __restrict__ wts,
    const int* __restrict__ lists, const int* __restrict__ ntiles,
    const int4* __restrict__ table, float* __restrict__ out) {
  int tm = blockIdx.x >> 3, tn = blockIdx.x & 7;
  if (tm >= ntiles[slot]) return;
  int4 ent = table[slot * NTM + tm];
  int e = ent.x, start = ent.y, rows = ent.z;
  int n0 = tn * 128;

  __shared__ __align__(16) u16 Al[BM * BK];   // 8 KB, linear (global_load_lds dest)
  __shared__ __align__(16) u16 Bl[BM * BK];   // 8 KB
  __shared__ int   tok[BM];
  __shared__ float wt[BM];

  int tid = threadIdx.x;
  if (tid < BM) {
    int t = 0; float w = 0.f;
    if (tid < rows) {
      t = lists[slot * N_TOK + start + tid];
      w = wts[t * 2 + slot];
    }
    tok[tid] = t; wt[tid] = w;
  }
  __syncthreads();

  int lane = tid & 63, wid = tid >> 6;
  // staging: idx = half*256 + tid -> row idx>>2, 8-elem seg (idx&3)*8
  // LDS byte addr (idx>>2)*64 + (idx&3)*16 == half*4096 + wid*1024 + lane*16 (linear)
  int r0 = tid >> 2, seg = (tid & 3) * 8;
  int r1 = (tid + 256) >> 2;
  size_t aoff0 = (size_t)tok[r0] * DIM + seg;
  size_t aoff1 = (size_t)tok[r1] * DIM + seg;
  size_t boff0 = ((size_t)e * DIM + (n0 + r0)) * DIM + seg;
  size_t boff1 = ((size_t)e * DIM + (n0 + r1)) * DIM + seg;
  char* a_dst0 = (char*)Al + wid * 1024;
  char* a_dst1 = (char*)Al + 4096 + wid * 1024;
  char* b_dst0 = (char*)Bl + wid * 1024;
  char* b_dst1 = (char*)Bl + 4096 + wid * 1024;

  f32x4 acc[4][4] = {};
  int wm = wid >> 1, wn = wid & 1;
  int lrow = lane & 15, lk = (lane >> 4) * 8;

#pragma unroll 1
  for (int term = 0; term < 3; ++term) {
    const u16* asrc = (term == 2) ? xl : xh;
    const u16* bsrc = (term == 1) ? Wl : Wh;
    const u16* ap0 = asrc + aoff0;
    const u16* ap1 = asrc + aoff1;
    const u16* bp0 = bsrc + boff0;
    const u16* bp1 = bsrc + boff1;
#pragma unroll 1
    for (int col = 0; col < DIM; col += BK) {
      gload_lds16(a_dst0, ap0 + col);
      gload_lds16(a_dst1, ap1 + col);
      gload_lds16(b_dst0, bp0 + col);
      gload_lds16(b_dst1, bp1 + col);
      __syncthreads();   // compiler drains vmcnt before s_barrier

      short8 a[4], b[4];
#pragma unroll
      for (int mi = 0; mi < 4; ++mi)
        a[mi] = *(const short8*)&Al[(wm * 64 + mi * 16 + lrow) * BK + lk];
#pragma unroll
      for (int ni = 0; ni < 4; ++ni)
        b[ni] = *(const short8*)&Bl[(wn * 64 + ni * 16 + lrow) * BK + lk];
#pragma unroll
      for (int mi = 0; mi < 4; ++mi)
#pragma unroll
        for (int ni = 0; ni < 4; ++ni)
          acc[mi][ni] = __builtin_amdgcn_mfma_f32_16x16x32_bf16(
              a[mi], b[ni], acc[mi][ni], 0, 0, 0);
      __syncthreads();
    }
  }

  // epilogue: out[t] (slot0) = w*(acc+bias); slot1: +=
#pragma unroll
  for (int mi = 0; mi < 4; ++mi) {
    int rbase = wm * 64 + mi * 16 + (lane >> 4) * 4;
#pragma unroll
    for (int ni = 0; ni < 4; ++ni) {
      int c = n0 + wn * 64 + ni * 16 + (lane & 15);
      float bv = eb[e * DIM + c];
#pragma unroll
      for (int j = 0; j < 4; ++j) {
        int r = rbase + j;
        if (r < rows) {
          float v = wt[r] * (acc[mi][ni][j] + bv);
          size_t oidx = (size_t)tok[r] * DIM + c;
          if (slot == 0) out[oidx] = v;
          else           out[oidx] += v;
        }
      }
    }
  }
}

// ---------------- launch ----------------
extern "C" void kernel_launch(void* const* d_in, const int* in_sizes, int n_in,
                              void* d_out, int out_size, void* d_ws, size_t ws_size,
                              hipStream_t stream) {
  const float* x  = (const float*)d_in[0];
  const float* gW = (const float*)d_in[1];
  const float* gb = (const float*)d_in[2];
  const float* eW = (const float*)d_in[3];
  const float* eb = (const float*)d_in[4];
  float* out = (float*)d_out;

  char* ws = (char*)d_ws;
  size_t o = 0;
  u16* xh = (u16*)(ws + o); o += (size_t)N_TOK * DIM * 2;      //  64 MiB
  u16* xl = (u16*)(ws + o); o += (size_t)N_TOK * DIM * 2;      //  64 MiB
  u16* Wh = (u16*)(ws + o); o += (size_t)NEXP * DIM * DIM * 2; //  16 MiB
  u16* Wl = (u16*)(ws + o); o += (size_t)NEXP * DIM * DIM * 2; //  16 MiB
  float* wts = (float*)(ws + o); o += (size_t)N_TOK * 2 * 4;
  int* eids  = (int*)(ws + o);   o += (size_t)N_TOK * 2 * 4;
  int* lists = (int*)(ws + o);   o += (size_t)2 * N_TOK * 4;
  Ctrl* ctrl = (Ctrl*)(ws + o);  o += sizeof(Ctrl);
  // total ~161 MiB; assumed <= ws_size

  hipMemsetAsync(ctrl->counts, 0, 16 * sizeof(int), stream);

  k_convert_w<<<2048, 256, 0, stream>>>((const float4*)eW, (ushort4*)Wh, (ushort4*)Wl);
  k_gate<<<512, 256, 0, stream>>>(x, gW, gb, xh, xl, wts, eids, ctrl->counts);
  k_scan<<<1, 64, 0, stream>>>(ctrl);
  k_lists<<<N_TOK / 256, 256, 0, stream>>>(eids, ctrl->cursors, lists);
  k_gemm<<<NTM * 8, 256, 0, stream>>>(0, xh, xl, Wh, Wl, eb, wts, lists,
                                      ctrl->ntiles, ctrl->table, out);
  k_gemm<<<NTM * 8, 256, 0, stream>>>(1, xh, xl, Wh, Wl, eb, wts, lists,
                                      ctrl->ntiles, ctrl->table, out);
}